// Round 2
// baseline (2491.261 us; speedup 1.0000x reference)
//
#include <hip/hip_runtime.h>
#include <math.h>

#define NN 100000
#define NE 1600000
#define HID 64
#define OUTC 32
#define NHEAD 4
#define C1 16
#define NEG 0.2f

__device__ __forceinline__ void atomicMaxFloat(float* addr, float val) {
    if (val >= 0.f) {
        atomicMax((int*)addr, __float_as_int(val));
    } else {
        atomicMin((unsigned int*)addr, __float_as_uint(val));
    }
}

__global__ __launch_bounds__(256) void fill_kernel(float* p, float v, int n) {
    int i = blockIdx.x * blockDim.x + threadIdx.x;
    if (i < n) p[i] = v;
}

// xl1 = x @ Wl1, xr1 = x @ Wr1   (x: [N,4], W: [4,64])
__global__ __launch_bounds__(256) void lin1_kernel(const float* __restrict__ x,
                                                   const float* __restrict__ Wl,
                                                   const float* __restrict__ Wr,
                                                   float* __restrict__ xl,
                                                   float* __restrict__ xr) {
    __shared__ float sWl[4 * HID], sWr[4 * HID];
    for (int i = threadIdx.x; i < 4 * HID; i += blockDim.x) {
        sWl[i] = Wl[i];
        sWr[i] = Wr[i];
    }
    __syncthreads();
    int idx = blockIdx.x * blockDim.x + threadIdx.x;
    int stride = gridDim.x * blockDim.x;
    const float4* x4 = (const float4*)x;
    for (; idx < NN * HID; idx += stride) {
        int n = idx >> 6, c = idx & 63;
        float4 xv = x4[n];
        float vl = xv.x * sWl[c] + xv.y * sWl[64 + c] + xv.z * sWl[128 + c] + xv.w * sWl[192 + c];
        float vr = xv.x * sWr[c] + xv.y * sWr[64 + c] + xv.z * sWr[128 + c] + xv.w * sWr[192 + c];
        xl[idx] = vl;
        xr[idx] = vr;
    }
}

// Edge pass 1 (layer1): e[eid][h] = sum_c lrelu(xl[s]+xr[d]) * att ; atomicMax emax
// 16 lanes per edge, each lane = 4 channels (float4). head = lane16/4.
__global__ __launch_bounds__(256) void att1_kernel(const int* __restrict__ ei,
                                                   const float* __restrict__ xl,
                                                   const float* __restrict__ xr,
                                                   const float* __restrict__ att,
                                                   float* __restrict__ e1,
                                                   float* __restrict__ emax) {
    int gid = blockIdx.x * blockDim.x + threadIdx.x;
    int lane16 = gid & 15;
    float4 av = *(const float4*)(att + lane16 * 4);  // att flat [64] == channel index
    int stride = (gridDim.x * blockDim.x) >> 4;
    for (int eid = gid >> 4; eid < NE; eid += stride) {
        int s = ei[eid];
        int d = ei[NE + eid];
        float4 l = *(const float4*)(xl + s * 64 + lane16 * 4);
        float4 r = *(const float4*)(xr + d * 64 + lane16 * 4);
        float m0 = l.x + r.x, m1 = l.y + r.y, m2 = l.z + r.z, m3 = l.w + r.w;
        m0 = m0 > 0.f ? m0 : NEG * m0;
        m1 = m1 > 0.f ? m1 : NEG * m1;
        m2 = m2 > 0.f ? m2 : NEG * m2;
        m3 = m3 > 0.f ? m3 : NEG * m3;
        float v = m0 * av.x + m1 * av.y + m2 * av.z + m3 * av.w;
        v += __shfl_xor(v, 1);
        v += __shfl_xor(v, 2);
        if ((lane16 & 3) == 0) {
            int h = lane16 >> 2;
            e1[eid * 4 + h] = v;
            atomicMaxFloat(&emax[d * 4 + h], v);
        }
    }
}

// Edge pass 2 (layer1): ee = exp(e - emax[dst]); denom += ee  (thread per edge*head)
__global__ __launch_bounds__(256) void soft1_kernel(const int* __restrict__ ei,
                                                    float* __restrict__ e1,
                                                    const float* __restrict__ emax,
                                                    float* __restrict__ denom) {
    int i = blockIdx.x * blockDim.x + threadIdx.x;
    int stride = gridDim.x * blockDim.x;
    for (; i < NE * 4; i += stride) {
        int eid = i >> 2, h = i & 3;
        int d = ei[NE + eid];
        float ee = __expf(e1[i] - emax[d * 4 + h]);
        e1[i] = ee;
        atomicAdd(&denom[d * 4 + h], ee);
    }
}

// Edge pass 3 (layer1): hacc[dst] += xl[src] * alpha  (16 lanes/edge)
__global__ __launch_bounds__(256) void aggr1_kernel(const int* __restrict__ ei,
                                                    const float* __restrict__ e1,
                                                    const float* __restrict__ denom,
                                                    const float* __restrict__ xl,
                                                    float* __restrict__ hacc) {
    int gid = blockIdx.x * blockDim.x + threadIdx.x;
    int lane16 = gid & 15;
    int h = lane16 >> 2;
    int stride = (gridDim.x * blockDim.x) >> 4;
    for (int eid = gid >> 4; eid < NE; eid += stride) {
        int s = ei[eid];
        int d = ei[NE + eid];
        float alpha = e1[eid * 4 + h] / denom[d * 4 + h];
        float4 l = *(const float4*)(xl + s * 64 + lane16 * 4);
        float* base = hacc + d * 64 + lane16 * 4;
        atomicAdd(base + 0, l.x * alpha);
        atomicAdd(base + 1, l.y * alpha);
        atomicAdd(base + 2, l.z * alpha);
        atomicAdd(base + 3, l.w * alpha);
    }
}

// LayerNorm(hacc + b1)*g1+be1 then ELU, in place. One wave (64 lanes) per node.
__global__ __launch_bounds__(256) void ln_elu_kernel(float* __restrict__ hacc,
                                                     const float* __restrict__ b1,
                                                     const float* __restrict__ g1,
                                                     const float* __restrict__ be1) {
    int node = blockIdx.x * 4 + (threadIdx.x >> 6);
    int lane = threadIdx.x & 63;
    if (node >= NN) return;
    float v = hacc[node * 64 + lane] + b1[lane];
    float s = v;
    for (int off = 1; off < 64; off <<= 1) s += __shfl_xor(s, off);
    float mu = s * (1.f / 64.f);
    float dv = v - mu;
    float q = dv * dv;
    for (int off = 1; off < 64; off <<= 1) q += __shfl_xor(q, off);
    float inv = rsqrtf(q * (1.f / 64.f) + 1e-5f);
    float y = dv * inv * g1[lane] + be1[lane];
    y = y > 0.f ? y : expm1f(y);
    hacc[node * 64 + lane] = y;
}

// xl2 = h @ Wl2, xr2 = h @ Wr2  (h: [N,64], W: [64,32]). Block: 8 nodes x 32 cols.
__global__ __launch_bounds__(256) void lin2_kernel(const float* __restrict__ h,
                                                   const float* __restrict__ Wl,
                                                   const float* __restrict__ Wr,
                                                   float* __restrict__ xl2,
                                                   float* __restrict__ xr2) {
    __shared__ float sW[2 * HID * OUTC];  // 16 KB
    __shared__ float sh[8 * HID];
    for (int i = threadIdx.x; i < HID * OUTC; i += blockDim.x) {
        sW[i] = Wl[i];
        sW[HID * OUTC + i] = Wr[i];
    }
    int node0 = blockIdx.x * 8;
    for (int i = threadIdx.x; i < 8 * HID; i += blockDim.x) {
        int n = node0 + (i >> 6);
        sh[i] = (n < NN) ? h[n * 64 + (i & 63)] : 0.f;
    }
    __syncthreads();
    int ln = threadIdx.x >> 5;
    int col = threadIdx.x & 31;
    int node = node0 + ln;
    if (node < NN) {
        float al = 0.f, ar = 0.f;
#pragma unroll
        for (int k = 0; k < HID; k++) {
            float hv = sh[ln * 64 + k];
            al += hv * sW[k * 32 + col];
            ar += hv * sW[HID * OUTC + k * 32 + col];
        }
        xl2[node * 32 + col] = al;
        xr2[node * 32 + col] = ar;
    }
}

// Edge pass 1 (layer2): 8 lanes per edge (1 head, 32 ch)
__global__ __launch_bounds__(256) void att2_kernel(const int* __restrict__ ei,
                                                   const float* __restrict__ xl2,
                                                   const float* __restrict__ xr2,
                                                   const float* __restrict__ att,
                                                   float* __restrict__ e2,
                                                   float* __restrict__ emax2) {
    int gid = blockIdx.x * blockDim.x + threadIdx.x;
    int lane8 = gid & 7;
    float4 av = *(const float4*)(att + lane8 * 4);
    int stride = (gridDim.x * blockDim.x) >> 3;
    for (int eid = gid >> 3; eid < NE; eid += stride) {
        int s = ei[eid];
        int d = ei[NE + eid];
        float4 l = *(const float4*)(xl2 + s * 32 + lane8 * 4);
        float4 r = *(const float4*)(xr2 + d * 32 + lane8 * 4);
        float m0 = l.x + r.x, m1 = l.y + r.y, m2 = l.z + r.z, m3 = l.w + r.w;
        m0 = m0 > 0.f ? m0 : NEG * m0;
        m1 = m1 > 0.f ? m1 : NEG * m1;
        m2 = m2 > 0.f ? m2 : NEG * m2;
        m3 = m3 > 0.f ? m3 : NEG * m3;
        float v = m0 * av.x + m1 * av.y + m2 * av.z + m3 * av.w;
        v += __shfl_xor(v, 1);
        v += __shfl_xor(v, 2);
        v += __shfl_xor(v, 4);
        if (lane8 == 0) {
            e2[eid] = v;
            atomicMaxFloat(&emax2[d], v);
        }
    }
}

__global__ __launch_bounds__(256) void soft2_kernel(const int* __restrict__ ei,
                                                    float* __restrict__ e2,
                                                    const float* __restrict__ emax2,
                                                    float* __restrict__ denom2) {
    int i = blockIdx.x * blockDim.x + threadIdx.x;
    int stride = gridDim.x * blockDim.x;
    for (; i < NE; i += stride) {
        int d = ei[NE + i];
        float ee = __expf(e2[i] - emax2[d]);
        e2[i] = ee;
        atomicAdd(&denom2[d], ee);
    }
}

__global__ __launch_bounds__(256) void aggr2_kernel(const int* __restrict__ ei,
                                                    const float* __restrict__ e2,
                                                    const float* __restrict__ denom2,
                                                    const float* __restrict__ xl2,
                                                    float* __restrict__ h2acc) {
    int gid = blockIdx.x * blockDim.x + threadIdx.x;
    int lane8 = gid & 7;
    int stride = (gridDim.x * blockDim.x) >> 3;
    for (int eid = gid >> 3; eid < NE; eid += stride) {
        int s = ei[eid];
        int d = ei[NE + eid];
        float alpha = e2[eid] / denom2[d];
        float4 l = *(const float4*)(xl2 + s * 32 + lane8 * 4);
        float* base = h2acc + d * 32 + lane8 * 4;
        atomicAdd(base + 0, l.x * alpha);
        atomicAdd(base + 1, l.y * alpha);
        atomicAdd(base + 2, l.z * alpha);
        atomicAdd(base + 3, l.w * alpha);
    }
}

// Final LayerNorm over 32 channels -> d_out. 32 lanes per node.
__global__ __launch_bounds__(256) void ln2_kernel(const float* __restrict__ h2,
                                                  const float* __restrict__ b2,
                                                  const float* __restrict__ g2,
                                                  const float* __restrict__ be2,
                                                  float* __restrict__ out) {
    int node = blockIdx.x * 8 + (threadIdx.x >> 5);
    int lane = threadIdx.x & 31;
    if (node >= NN) return;
    float v = h2[node * 32 + lane] + b2[lane];
    float s = v;
    for (int off = 1; off < 32; off <<= 1) s += __shfl_xor(s, off);
    float mu = s * (1.f / 32.f);
    float dv = v - mu;
    float q = dv * dv;
    for (int off = 1; off < 32; off <<= 1) q += __shfl_xor(q, off);
    float inv = rsqrtf(q * (1.f / 32.f) + 1e-5f);
    out[node * 32 + lane] = dv * inv * g2[lane] + be2[lane];
}

extern "C" void kernel_launch(void* const* d_in, const int* in_sizes, int n_in,
                              void* d_out, int out_size, void* d_ws, size_t ws_size,
                              hipStream_t stream) {
    const float* x   = (const float*)d_in[0];
    const int* ei    = (const int*)d_in[1];
    const float* Wl1 = (const float*)d_in[2];
    const float* Wr1 = (const float*)d_in[3];
    const float* att1 = (const float*)d_in[4];
    const float* b1  = (const float*)d_in[5];
    const float* g1  = (const float*)d_in[6];
    const float* be1 = (const float*)d_in[7];
    const float* Wl2 = (const float*)d_in[8];
    const float* Wr2 = (const float*)d_in[9];
    const float* att2 = (const float*)d_in[10];
    const float* b2  = (const float*)d_in[11];
    const float* g2  = (const float*)d_in[12];
    const float* be2 = (const float*)d_in[13];
    float* out = (float*)d_out;

    float* ws = (float*)d_ws;
    // Region A: xl1 [N*64]; later reused as e2 [E]
    float* xl1 = ws;
    // Region B: xr1 [N*64]; reused as hacc/h [N*64]; reused as h2acc [N*32]
    float* xr1 = xl1 + (size_t)NN * 64;
    // Region C: e1/ee1 [E*4]; reused as xl2 [N*32] + xr2 [N*32]
    float* e1 = xr1 + (size_t)NN * 64;
    // Small region: emax1 [N*4] emax2 [N] denom1 [N*4] denom2 [N]
    float* emax1 = e1 + (size_t)NE * 4;
    float* emax2 = emax1 + (size_t)NN * 4;
    float* denom1 = emax2 + NN;
    float* denom2 = denom1 + (size_t)NN * 4;

    float* hacc = xr1;   // after att1 pass, xr1 is dead
    float* xl2 = e1;     // after aggr1, e1 is dead
    float* xr2 = e1 + (size_t)NN * 32;
    float* e2 = xl1;     // after aggr1, xl1 is dead
    float* h2acc = xr1;  // after lin2, h is dead

    const int B = 256;

    // init: emax1+emax2 = -inf (contiguous 5N floats), denom1+denom2 = 0 (contiguous 5N)
    fill_kernel<<<(NN * 5 + B - 1) / B, B, 0, stream>>>(emax1, -INFINITY, NN * 5);
    hipMemsetAsync(denom1, 0, (size_t)NN * 5 * sizeof(float), stream);

    // ---- layer 1 ----
    lin1_kernel<<<(NN * 64 + B - 1) / B, B, 0, stream>>>(x, Wl1, Wr1, xl1, xr1);
    att1_kernel<<<(NE * 16 + B - 1) / B, B, 0, stream>>>(ei, xl1, xr1, att1, e1, emax1);
    soft1_kernel<<<(NE * 4 + B - 1) / B, B, 0, stream>>>(ei, e1, emax1, denom1);
    hipMemsetAsync(hacc, 0, (size_t)NN * 64 * sizeof(float), stream);  // xr1 dead now
    aggr1_kernel<<<(NE * 16 + B - 1) / B, B, 0, stream>>>(ei, e1, denom1, xl1, hacc);
    ln_elu_kernel<<<(NN + 3) / 4, B, 0, stream>>>(hacc, b1, g1, be1);

    // ---- layer 2 ----
    lin2_kernel<<<(NN + 7) / 8, B, 0, stream>>>(hacc, Wl2, Wr2, xl2, xr2);
    att2_kernel<<<(NE * 8 + B - 1) / B, B, 0, stream>>>(ei, xl2, xr2, att2, e2, emax2);
    soft2_kernel<<<(NE + B - 1) / B, B, 0, stream>>>(ei, e2, emax2, denom2);
    hipMemsetAsync(h2acc, 0, (size_t)NN * 32 * sizeof(float), stream);  // h dead now
    aggr2_kernel<<<(NE * 8 + B - 1) / B, B, 0, stream>>>(ei, e2, denom2, xl2, h2acc);
    ln2_kernel<<<(NN + 7) / 8, B, 0, stream>>>(h2acc, b2, g2, be2, out);
}

// Round 3
// 599.655 us; speedup vs baseline: 4.1545x; 4.1545x over previous
//
#include <hip/hip_runtime.h>
#include <math.h>

#define NN 100000
#define NE 1600000
#define HID 64
#define OUTC 32
#define NEG 0.2f

// ---------- CSR build ----------

__global__ __launch_bounds__(256) void hist_kernel(const int* __restrict__ ei,
                                                   int* __restrict__ deg) {
    int i = blockIdx.x * blockDim.x + threadIdx.x;
    if (i < NE) atomicAdd(&deg[ei[NE + i]], 1);
}

// single-workgroup chunked exclusive scan: deg[N] -> rowptr[N] (+ rowptr[N]=E), cursor copy
__global__ __launch_bounds__(1024) void scan_kernel(const int* __restrict__ deg,
                                                    int* __restrict__ rowptr,
                                                    int* __restrict__ cursor) {
    __shared__ int wsum[16];
    __shared__ int s_carry;
    int tid = threadIdx.x;
    int lane = tid & 63, wid = tid >> 6;
    if (tid == 0) s_carry = 0;
    __syncthreads();
    for (int base = 0; base < NN; base += 1024) {
        int i = base + tid;
        int v = (i < NN) ? deg[i] : 0;
        int sv = v;
        for (int s = 1; s < 64; s <<= 1) {
            int t = __shfl_up(sv, s);
            if (lane >= s) sv += t;
        }
        if (lane == 63) wsum[wid] = sv;
        __syncthreads();
        if (wid == 0) {
            int w = (lane < 16) ? wsum[lane] : 0;
            for (int s = 1; s < 16; s <<= 1) {
                int t = __shfl_up(w, s);
                if (lane >= s) w += t;
            }
            if (lane < 16) wsum[lane] = w;
        }
        __syncthreads();
        int waveoff = (wid > 0) ? wsum[wid - 1] : 0;
        int carry = s_carry;
        int excl = carry + waveoff + sv - v;
        if (i < NN) { rowptr[i] = excl; cursor[i] = excl; }
        __syncthreads();
        if (tid == 1023) s_carry = carry + wsum[15];
        __syncthreads();
    }
    if (tid == 0) rowptr[NN] = NE;
}

__global__ __launch_bounds__(256) void scatter_kernel(const int* __restrict__ ei,
                                                      int* __restrict__ cursor,
                                                      int* __restrict__ csr_src) {
    int i = blockIdx.x * blockDim.x + threadIdx.x;
    if (i < NE) {
        int d = ei[NE + i];
        int s = ei[i];
        int pos = atomicAdd(&cursor[d], 1);
        csr_src[pos] = s;
    }
}

// ---------- layer 1 ----------

// xl1 = x @ Wl1   (x: [N,4], W: [4,64])
__global__ __launch_bounds__(256) void lin1_kernel(const float* __restrict__ x,
                                                   const float* __restrict__ Wl,
                                                   float* __restrict__ xl) {
    __shared__ float sWl[4 * HID];
    for (int i = threadIdx.x; i < 4 * HID; i += blockDim.x) sWl[i] = Wl[i];
    __syncthreads();
    int idx = blockIdx.x * blockDim.x + threadIdx.x;
    int stride = gridDim.x * blockDim.x;
    const float4* x4 = (const float4*)x;
    for (; idx < NN * HID; idx += stride) {
        int n = idx >> 6, c = idx & 63;
        float4 xv = x4[n];
        xl[idx] = xv.x * sWl[c] + xv.y * sWl[64 + c] + xv.z * sWl[128 + c] + xv.w * sWl[192 + c];
    }
}

// Fused: per dst node (1 wave = 64 ch, head = lane/16): online-softmax GATv2
// aggregation over CSR edges, then +bias, LayerNorm, ELU -> h.
__global__ __launch_bounds__(256) void gather1_kernel(const int* __restrict__ rowptr,
                                                      const int* __restrict__ csr_src,
                                                      const float* __restrict__ x,
                                                      const float* __restrict__ Wr,
                                                      const float* __restrict__ att,
                                                      const float* __restrict__ xl,
                                                      const float* __restrict__ b1,
                                                      const float* __restrict__ g1,
                                                      const float* __restrict__ be1,
                                                      float* __restrict__ h) {
    __shared__ float sWr[4 * HID];
    __shared__ float satt[HID], sb[HID], sg[HID], sbe[HID];
    int tid = threadIdx.x;
    if (tid < 256) sWr[tid] = Wr[tid];
    if (tid < HID) {
        satt[tid] = att[tid];
        sb[tid] = b1[tid];
        sg[tid] = g1[tid];
        sbe[tid] = be1[tid];
    }
    __syncthreads();
    int node = blockIdx.x * 4 + (tid >> 6);
    if (node >= NN) return;
    int lane = tid & 63;
    int p0 = rowptr[node], p1 = rowptr[node + 1];

    // xr[dst] on the fly: x[dst] @ Wr
    float4 xd = *(const float4*)(x + node * 4);
    float xr = xd.x * sWr[lane] + xd.y * sWr[64 + lane] + xd.z * sWr[128 + lane] + xd.w * sWr[192 + lane];
    float a = satt[lane];

    float m = -INFINITY, ssum = 0.f, acc = 0.f;
    for (int p = p0; p < p1; p += 64) {
        int nvalid = min(64, p1 - p);
        int srcs = (p + lane < p1) ? csr_src[p + lane] : 0;
        for (int i = 0; i < nvalid; ++i) {
            int s = __shfl(srcs, i);
            float xls = xl[s * 64 + lane];
            float mm = xls + xr;
            mm = mm > 0.f ? mm : NEG * mm;
            float v = mm * a;
            v += __shfl_xor(v, 1);
            v += __shfl_xor(v, 2);
            v += __shfl_xor(v, 4);
            v += __shfl_xor(v, 8);  // per-head (16-lane group) logit
            float mn = fmaxf(m, v);
            float es = (m > -INFINITY) ? __expf(m - mn) : 0.f;
            float ev = __expf(v - mn);
            ssum = ssum * es + ev;
            acc = acc * es + ev * xls;
            m = mn;
        }
    }
    float val = (p1 > p0) ? acc / ssum : 0.f;
    val += sb[lane];
    // LayerNorm over 64 lanes
    float s = val;
    for (int off = 1; off < 64; off <<= 1) s += __shfl_xor(s, off);
    float mu = s * (1.f / 64.f);
    float dv = val - mu;
    float q = dv * dv;
    for (int off = 1; off < 64; off <<= 1) q += __shfl_xor(q, off);
    float inv = rsqrtf(q * (1.f / 64.f) + 1e-5f);
    float y = dv * inv * sg[lane] + sbe[lane];
    y = y > 0.f ? y : expm1f(y);
    h[node * 64 + lane] = y;
}

// ---------- layer 2 ----------

// xl2 = h @ Wl2, xr2 = h @ Wr2  (h: [N,64], W: [64,32]).
__global__ __launch_bounds__(256) void lin2_kernel(const float* __restrict__ h,
                                                   const float* __restrict__ Wl,
                                                   const float* __restrict__ Wr,
                                                   float* __restrict__ xl2,
                                                   float* __restrict__ xr2) {
    __shared__ float sW[2 * HID * OUTC];
    __shared__ float sh[8 * HID];
    for (int i = threadIdx.x; i < HID * OUTC; i += blockDim.x) {
        sW[i] = Wl[i];
        sW[HID * OUTC + i] = Wr[i];
    }
    int node0 = blockIdx.x * 8;
    for (int i = threadIdx.x; i < 8 * HID; i += blockDim.x) {
        int n = node0 + (i >> 6);
        sh[i] = (n < NN) ? h[n * 64 + (i & 63)] : 0.f;
    }
    __syncthreads();
    int ln = threadIdx.x >> 5;
    int col = threadIdx.x & 31;
    int node = node0 + ln;
    if (node < NN) {
        float al = 0.f, ar = 0.f;
#pragma unroll
        for (int k = 0; k < HID; k++) {
            float hv = sh[ln * 64 + k];
            al += hv * sW[k * 32 + col];
            ar += hv * sW[HID * OUTC + k * 32 + col];
        }
        xl2[node * 32 + col] = al;
        xr2[node * 32 + col] = ar;
    }
}

// Fused layer-2: per dst node 1 wave; 2 edges/iter (half-wave = 32 ch each),
// online softmax per half, merged at the end; + bias, LayerNorm -> out.
__global__ __launch_bounds__(256) void gather2_kernel(const int* __restrict__ rowptr,
                                                      const int* __restrict__ csr_src,
                                                      const float* __restrict__ xl2,
                                                      const float* __restrict__ xr2,
                                                      const float* __restrict__ att,
                                                      const float* __restrict__ b2,
                                                      const float* __restrict__ g2,
                                                      const float* __restrict__ be2,
                                                      float* __restrict__ out) {
    __shared__ float satt[OUTC], sb[OUTC], sg[OUTC], sbe[OUTC];
    int tid = threadIdx.x;
    if (tid < OUTC) {
        satt[tid] = att[tid];
        sb[tid] = b2[tid];
        sg[tid] = g2[tid];
        sbe[tid] = be2[tid];
    }
    __syncthreads();
    int node = blockIdx.x * 4 + (tid >> 6);
    if (node >= NN) return;
    int lane = tid & 63;
    int half = lane >> 5;
    int ch = lane & 31;
    int p0 = rowptr[node], p1 = rowptr[node + 1];

    float xr = xr2[node * 32 + ch];
    float a = satt[ch];

    float m = -INFINITY, ssum = 0.f, acc = 0.f;
    for (int p = p0; p < p1; p += 64) {
        int nvalid = min(64, p1 - p);
        int srcs = (p + lane < p1) ? csr_src[p + lane] : 0;
        for (int i = 0; i < nvalid; i += 2) {
            int idx = i + half;
            bool ok = idx < nvalid;
            int s = __shfl(srcs, min(idx, 63));
            float xls = ok ? xl2[s * 32 + ch] : 0.f;
            float mm = xls + xr;
            mm = mm > 0.f ? mm : NEG * mm;
            float v = mm * a;
            v += __shfl_xor(v, 1);
            v += __shfl_xor(v, 2);
            v += __shfl_xor(v, 4);
            v += __shfl_xor(v, 8);
            v += __shfl_xor(v, 16);  // 32-lane (half-wave) reduce
            if (!ok) v = -INFINITY;
            float mn = fmaxf(m, v);
            float es = (m > -INFINITY) ? __expf(m - mn) : 0.f;
            float ev = (v > -INFINITY) ? __expf(v - mn) : 0.f;
            ssum = ssum * es + ev;
            acc = acc * es + ev * xls;
            m = mn;
        }
    }
    // merge halves
    float mo = __shfl_xor(m, 32);
    float so = __shfl_xor(ssum, 32);
    float ao = __shfl_xor(acc, 32);
    float M = fmaxf(m, mo);
    float ea = (m > -INFINITY) ? __expf(m - M) : 0.f;
    float eb = (mo > -INFINITY) ? __expf(mo - M) : 0.f;
    float S = ssum * ea + so * eb;
    float A = acc * ea + ao * eb;
    float val = (p1 > p0) ? A / S : 0.f;
    val += sb[ch];
    // LayerNorm over 32 channels (stays within half-wave)
    float s = val;
    for (int off = 1; off < 32; off <<= 1) s += __shfl_xor(s, off);
    float mu = s * (1.f / 32.f);
    float dv = val - mu;
    float q = dv * dv;
    for (int off = 1; off < 32; off <<= 1) q += __shfl_xor(q, off);
    float inv = rsqrtf(q * (1.f / 32.f) + 1e-5f);
    if (half == 0) out[node * 32 + ch] = dv * inv * sg[ch] + sbe[ch];
}

extern "C" void kernel_launch(void* const* d_in, const int* in_sizes, int n_in,
                              void* d_out, int out_size, void* d_ws, size_t ws_size,
                              hipStream_t stream) {
    const float* x    = (const float*)d_in[0];
    const int* ei     = (const int*)d_in[1];
    const float* Wl1  = (const float*)d_in[2];
    const float* Wr1  = (const float*)d_in[3];
    const float* att1 = (const float*)d_in[4];
    const float* b1   = (const float*)d_in[5];
    const float* g1   = (const float*)d_in[6];
    const float* be1  = (const float*)d_in[7];
    const float* Wl2  = (const float*)d_in[8];
    const float* Wr2  = (const float*)d_in[9];
    const float* att2 = (const float*)d_in[10];
    const float* b2   = (const float*)d_in[11];
    const float* g2   = (const float*)d_in[12];
    const float* be2  = (const float*)d_in[13];
    float* out = (float*)d_out;

    float* ws = (float*)d_ws;
    // Region A: xl1 [N*64]; after gather1 reused as xl2 [N*32] + xr2 [N*32]
    float* xl1 = ws;
    float* xl2 = xl1;
    float* xr2 = xl1 + (size_t)NN * 32;
    // Region B: h [N*64]
    float* h = xl1 + (size_t)NN * 64;
    // Int region: deg [N], rowptr [N+1], cursor [N], csr_src [E]
    int* deg = (int*)(h + (size_t)NN * 64);
    int* rowptr = deg + NN;
    int* cursor = rowptr + NN + 1;
    int* csr_src = cursor + NN;

    const int B = 256;

    // ---- CSR build (shared by both layers) ----
    hipMemsetAsync(deg, 0, (size_t)NN * sizeof(int), stream);
    hist_kernel<<<(NE + B - 1) / B, B, 0, stream>>>(ei, deg);
    scan_kernel<<<1, 1024, 0, stream>>>(deg, rowptr, cursor);
    scatter_kernel<<<(NE + B - 1) / B, B, 0, stream>>>(ei, cursor, csr_src);

    // ---- layer 1 ----
    lin1_kernel<<<(NN * 64 + B - 1) / B, B, 0, stream>>>(x, Wl1, xl1);
    gather1_kernel<<<(NN + 3) / 4, B, 0, stream>>>(rowptr, csr_src, x, Wr1, att1, xl1,
                                                   b1, g1, be1, h);

    // ---- layer 2 ----
    lin2_kernel<<<(NN + 7) / 8, B, 0, stream>>>(h, Wl2, Wr2, xl2, xr2);
    gather2_kernel<<<(NN + 3) / 4, B, 0, stream>>>(rowptr, csr_src, xl2, xr2, att2,
                                                   b2, g2, be2, out);
}

// Round 4
// 394.658 us; speedup vs baseline: 6.3125x; 1.5194x over previous
//
#include <hip/hip_runtime.h>
#include <math.h>

#define NN 100000
#define NE 1600000
#define HID 64
#define OUTC 32
#define NEG 0.2f
#define SCAN_CHUNK 1024
#define NCHUNK ((NN + SCAN_CHUNK - 1) / SCAN_CHUNK)

// ---------- CSR build ----------

__global__ __launch_bounds__(256) void hist_kernel(const int* __restrict__ ei,
                                                   int* __restrict__ deg) {
    int i = blockIdx.x * blockDim.x + threadIdx.x;
    if (i < NE) atomicAdd(&deg[ei[NE + i]], 1);
}

// per-chunk sums
__global__ __launch_bounds__(256) void scanA_kernel(const int* __restrict__ deg,
                                                    int* __restrict__ bsum) {
    int b = blockIdx.x;
    int base = b * SCAN_CHUNK;
    int tid = threadIdx.x;
    int v = 0;
    for (int i = tid; i < SCAN_CHUNK; i += 256) {
        int idx = base + i;
        v += (idx < NN) ? deg[idx] : 0;
    }
    for (int off = 1; off < 64; off <<= 1) v += __shfl_xor(v, off);
    __shared__ int ws[4];
    if ((tid & 63) == 0) ws[tid >> 6] = v;
    __syncthreads();
    if (tid == 0) bsum[b] = ws[0] + ws[1] + ws[2] + ws[3];
}

// exclusive scan of NCHUNK (=98) block sums, single wave
__global__ void scanB_kernel(const int* __restrict__ bsum, int* __restrict__ boff) {
    int lane = threadIdx.x;  // 64 threads
    int carry = 0;
    for (int base = 0; base < NCHUNK; base += 64) {
        int i = base + lane;
        int v = (i < NCHUNK) ? bsum[i] : 0;
        int sv = v;
        for (int s = 1; s < 64; s <<= 1) {
            int t = __shfl_up(sv, s);
            if (lane >= s) sv += t;
        }
        if (i < NCHUNK) boff[i] = carry + sv - v;
        carry += __shfl(sv, 63);
    }
}

// per-chunk exclusive scan + chunk offset -> rowptr, cursor
__global__ __launch_bounds__(256) void scanC_kernel(const int* __restrict__ deg,
                                                    const int* __restrict__ boff,
                                                    int* __restrict__ rowptr,
                                                    int* __restrict__ cursor) {
    int b = blockIdx.x;
    int tid = threadIdx.x;
    int lane = tid & 63, wid = tid >> 6;
    __shared__ int wsum[4];
    int i0 = b * SCAN_CHUNK + tid * 4;
    int d0 = (i0 + 0 < NN) ? deg[i0 + 0] : 0;
    int d1 = (i0 + 1 < NN) ? deg[i0 + 1] : 0;
    int d2 = (i0 + 2 < NN) ? deg[i0 + 2] : 0;
    int d3 = (i0 + 3 < NN) ? deg[i0 + 3] : 0;
    int t = d0 + d1 + d2 + d3;
    int st = t;
    for (int s = 1; s < 64; s <<= 1) {
        int u = __shfl_up(st, s);
        if (lane >= s) st += u;
    }
    if (lane == 63) wsum[wid] = st;
    __syncthreads();
    int woff = 0;
    for (int w = 0; w < wid; w++) woff += wsum[w];
    int excl = boff[b] + woff + st - t;
    if (i0 + 0 < NN) { rowptr[i0 + 0] = excl; cursor[i0 + 0] = excl; }
    excl += d0;
    if (i0 + 1 < NN) { rowptr[i0 + 1] = excl; cursor[i0 + 1] = excl; }
    excl += d1;
    if (i0 + 2 < NN) { rowptr[i0 + 2] = excl; cursor[i0 + 2] = excl; }
    excl += d2;
    if (i0 + 3 < NN) { rowptr[i0 + 3] = excl; cursor[i0 + 3] = excl; }
    if (b == 0 && tid == 0) rowptr[NN] = NE;
}

__global__ __launch_bounds__(256) void scatter_kernel(const int* __restrict__ ei,
                                                      int* __restrict__ cursor,
                                                      int* __restrict__ csr_src) {
    int i = blockIdx.x * blockDim.x + threadIdx.x;
    if (i < NE) {
        int d = ei[NE + i];
        int s = ei[i];
        int pos = atomicAdd(&cursor[d], 1);
        csr_src[pos] = s;
    }
}

// ---------- layer 1 ----------

// xl1 = x @ Wl1   (x: [N,4], W: [4,64])
__global__ __launch_bounds__(256) void lin1_kernel(const float* __restrict__ x,
                                                   const float* __restrict__ Wl,
                                                   float* __restrict__ xl) {
    __shared__ float sWl[4 * HID];
    for (int i = threadIdx.x; i < 4 * HID; i += blockDim.x) sWl[i] = Wl[i];
    __syncthreads();
    int idx = blockIdx.x * blockDim.x + threadIdx.x;
    int stride = gridDim.x * blockDim.x;
    const float4* x4 = (const float4*)x;
    for (; idx < NN * HID; idx += stride) {
        int n = idx >> 6, c = idx & 63;
        float4 xv = x4[n];
        xl[idx] = xv.x * sWl[c] + xv.y * sWl[64 + c] + xv.z * sWl[128 + c] + xv.w * sWl[192 + c];
    }
}

// Fused GATv2 layer-1 pull: 1 wave per dst node, 4 edges in flight
// (grp = lane>>4 is edge slot, sl = lane&15 covers channels sl*4..sl*4+3).
// No max-subtraction (logits bounded << 88). Ends with +bias, LN, ELU.
__global__ __launch_bounds__(256) void gather1_kernel(const int* __restrict__ rowptr,
                                                      const int* __restrict__ csr_src,
                                                      const float* __restrict__ x,
                                                      const float* __restrict__ Wr,
                                                      const float* __restrict__ att,
                                                      const float* __restrict__ xl,
                                                      const float* __restrict__ b1,
                                                      const float* __restrict__ g1,
                                                      const float* __restrict__ be1,
                                                      float* __restrict__ h) {
    __shared__ float sWr[4 * HID];
    __shared__ float satt[HID], sb[HID], sg[HID], sbe[HID];
    int tid = threadIdx.x;
    if (tid < 256) sWr[tid] = Wr[tid];
    if (tid < HID) {
        satt[tid] = att[tid];
        sb[tid] = b1[tid];
        sg[tid] = g1[tid];
        sbe[tid] = be1[tid];
    }
    __syncthreads();
    int node = blockIdx.x * 4 + (tid >> 6);
    if (node >= NN) return;
    int lane = tid & 63;
    int grp = lane >> 4;  // edge slot 0..3
    int sl = lane & 15;   // channel quad
    int ch = sl * 4;
    int p0 = rowptr[node], p1 = rowptr[node + 1];

    float4 xd = *(const float4*)(x + node * 4);
    float xr0 = xd.x * sWr[ch + 0] + xd.y * sWr[64 + ch + 0] + xd.z * sWr[128 + ch + 0] + xd.w * sWr[192 + ch + 0];
    float xr1 = xd.x * sWr[ch + 1] + xd.y * sWr[64 + ch + 1] + xd.z * sWr[128 + ch + 1] + xd.w * sWr[192 + ch + 1];
    float xr2 = xd.x * sWr[ch + 2] + xd.y * sWr[64 + ch + 2] + xd.z * sWr[128 + ch + 2] + xd.w * sWr[192 + ch + 2];
    float xr3 = xd.x * sWr[ch + 3] + xd.y * sWr[64 + ch + 3] + xd.z * sWr[128 + ch + 3] + xd.w * sWr[192 + ch + 3];
    float a0 = satt[ch + 0], a1 = satt[ch + 1], a2 = satt[ch + 2], a3 = satt[ch + 3];

    float ssum = 0.f;
    float ac0 = 0.f, ac1 = 0.f, ac2 = 0.f, ac3 = 0.f;
    for (int p = p0; p < p1; p += 64) {
        int cnt = min(64, p1 - p);
        int srcs = (lane < cnt) ? csr_src[p + lane] : 0;
        for (int j = 0; j < cnt; j += 4) {
            int idx = j + grp;
            bool ok = idx < cnt;
            int s = __shfl(srcs, ok ? idx : 0);
            float4 l4 = *(const float4*)(xl + (size_t)s * 64 + ch);
            float mm, vv;
            mm = l4.x + xr0; mm = mm > 0.f ? mm : NEG * mm; vv = mm * a0;
            mm = l4.y + xr1; mm = mm > 0.f ? mm : NEG * mm; vv += mm * a1;
            mm = l4.z + xr2; mm = mm > 0.f ? mm : NEG * mm; vv += mm * a2;
            mm = l4.w + xr3; mm = mm > 0.f ? mm : NEG * mm; vv += mm * a3;
            vv += __shfl_xor(vv, 1);
            vv += __shfl_xor(vv, 2);  // per-head logit (4 lanes = 16 ch)
            float ev = ok ? __expf(vv) : 0.f;
            ssum += ev;
            ac0 += ev * l4.x;
            ac1 += ev * l4.y;
            ac2 += ev * l4.z;
            ac3 += ev * l4.w;
        }
    }
    // merge the 4 edge groups
    ssum += __shfl_xor(ssum, 16);
    ac0 += __shfl_xor(ac0, 16); ac1 += __shfl_xor(ac1, 16);
    ac2 += __shfl_xor(ac2, 16); ac3 += __shfl_xor(ac3, 16);
    ssum += __shfl_xor(ssum, 32);
    ac0 += __shfl_xor(ac0, 32); ac1 += __shfl_xor(ac1, 32);
    ac2 += __shfl_xor(ac2, 32); ac3 += __shfl_xor(ac3, 32);
    float inv_s = (ssum > 0.f) ? 1.f / ssum : 0.f;
    float v0 = ac0 * inv_s + sb[ch + 0];
    float v1 = ac1 * inv_s + sb[ch + 1];
    float v2 = ac2 * inv_s + sb[ch + 2];
    float v3 = ac3 * inv_s + sb[ch + 3];
    // LayerNorm over 64 channels (each lane holds 4; groups hold identical copies)
    float s4 = v0 + v1 + v2 + v3;
    s4 += __shfl_xor(s4, 1); s4 += __shfl_xor(s4, 2);
    s4 += __shfl_xor(s4, 4); s4 += __shfl_xor(s4, 8);
    float mu = s4 * (1.f / 64.f);
    float d0 = v0 - mu, d1 = v1 - mu, d2 = v2 - mu, d3 = v3 - mu;
    float q4 = d0 * d0 + d1 * d1 + d2 * d2 + d3 * d3;
    q4 += __shfl_xor(q4, 1); q4 += __shfl_xor(q4, 2);
    q4 += __shfl_xor(q4, 4); q4 += __shfl_xor(q4, 8);
    float inv = rsqrtf(q4 * (1.f / 64.f) + 1e-5f);
    float y0 = d0 * inv * sg[ch + 0] + sbe[ch + 0];
    float y1 = d1 * inv * sg[ch + 1] + sbe[ch + 1];
    float y2 = d2 * inv * sg[ch + 2] + sbe[ch + 2];
    float y3 = d3 * inv * sg[ch + 3] + sbe[ch + 3];
    y0 = y0 > 0.f ? y0 : expm1f(y0);
    y1 = y1 > 0.f ? y1 : expm1f(y1);
    y2 = y2 > 0.f ? y2 : expm1f(y2);
    y3 = y3 > 0.f ? y3 : expm1f(y3);
    if (grp == 0) {
        float4 o = make_float4(y0, y1, y2, y3);
        *(float4*)(h + (size_t)node * 64 + ch) = o;
    }
}

// ---------- layer 2 ----------

// xl2 = h @ Wl2, xr2 = h @ Wr2  (h: [N,64], W: [64,32]).
__global__ __launch_bounds__(256) void lin2_kernel(const float* __restrict__ h,
                                                   const float* __restrict__ Wl,
                                                   const float* __restrict__ Wr,
                                                   float* __restrict__ xl2,
                                                   float* __restrict__ xr2) {
    __shared__ float sW[2 * HID * OUTC];
    __shared__ float sh[8 * HID];
    for (int i = threadIdx.x; i < HID * OUTC; i += blockDim.x) {
        sW[i] = Wl[i];
        sW[HID * OUTC + i] = Wr[i];
    }
    int node0 = blockIdx.x * 8;
    for (int i = threadIdx.x; i < 8 * HID; i += blockDim.x) {
        int n = node0 + (i >> 6);
        sh[i] = (n < NN) ? h[n * 64 + (i & 63)] : 0.f;
    }
    __syncthreads();
    int ln = threadIdx.x >> 5;
    int col = threadIdx.x & 31;
    int node = node0 + ln;
    if (node < NN) {
        float al = 0.f, ar = 0.f;
#pragma unroll
        for (int k = 0; k < HID; k++) {
            float hv = sh[ln * 64 + k];
            al += hv * sW[k * 32 + col];
            ar += hv * sW[HID * OUTC + k * 32 + col];
        }
        xl2[node * 32 + col] = al;
        xr2[node * 32 + col] = ar;
    }
}

// Fused GATv2 layer-2 pull: 1 wave per dst node, 8 edges in flight
// (grp = lane>>3 edge slot, sl = lane&7 covers channels sl*4..sl*4+3).
__global__ __launch_bounds__(256) void gather2_kernel(const int* __restrict__ rowptr,
                                                      const int* __restrict__ csr_src,
                                                      const float* __restrict__ xl2,
                                                      const float* __restrict__ xr2,
                                                      const float* __restrict__ att,
                                                      const float* __restrict__ b2,
                                                      const float* __restrict__ g2,
                                                      const float* __restrict__ be2,
                                                      float* __restrict__ out) {
    __shared__ float satt[OUTC], sb[OUTC], sg[OUTC], sbe[OUTC];
    int tid = threadIdx.x;
    if (tid < OUTC) {
        satt[tid] = att[tid];
        sb[tid] = b2[tid];
        sg[tid] = g2[tid];
        sbe[tid] = be2[tid];
    }
    __syncthreads();
    int node = blockIdx.x * 4 + (tid >> 6);
    if (node >= NN) return;
    int lane = tid & 63;
    int grp = lane >> 3;  // edge slot 0..7
    int sl = lane & 7;    // channel quad
    int ch = sl * 4;
    int p0 = rowptr[node], p1 = rowptr[node + 1];

    float4 xr = *(const float4*)(xr2 + (size_t)node * 32 + ch);
    float a0 = satt[ch + 0], a1 = satt[ch + 1], a2 = satt[ch + 2], a3 = satt[ch + 3];

    float ssum = 0.f;
    float ac0 = 0.f, ac1 = 0.f, ac2 = 0.f, ac3 = 0.f;
    for (int p = p0; p < p1; p += 64) {
        int cnt = min(64, p1 - p);
        int srcs = (lane < cnt) ? csr_src[p + lane] : 0;
        for (int j = 0; j < cnt; j += 8) {
            int idx = j + grp;
            bool ok = idx < cnt;
            int s = __shfl(srcs, ok ? idx : 0);
            float4 l4 = *(const float4*)(xl2 + (size_t)s * 32 + ch);
            float mm, vv;
            mm = l4.x + xr.x; mm = mm > 0.f ? mm : NEG * mm; vv = mm * a0;
            mm = l4.y + xr.y; mm = mm > 0.f ? mm : NEG * mm; vv += mm * a1;
            mm = l4.z + xr.z; mm = mm > 0.f ? mm : NEG * mm; vv += mm * a2;
            mm = l4.w + xr.w; mm = mm > 0.f ? mm : NEG * mm; vv += mm * a3;
            vv += __shfl_xor(vv, 1);
            vv += __shfl_xor(vv, 2);
            vv += __shfl_xor(vv, 4);  // 8 lanes = full 32-ch logit
            float ev = ok ? __expf(vv) : 0.f;
            ssum += ev;
            ac0 += ev * l4.x;
            ac1 += ev * l4.y;
            ac2 += ev * l4.z;
            ac3 += ev * l4.w;
        }
    }
    // merge the 8 edge groups
    for (int off = 8; off < 64; off <<= 1) {
        ssum += __shfl_xor(ssum, off);
        ac0 += __shfl_xor(ac0, off); ac1 += __shfl_xor(ac1, off);
        ac2 += __shfl_xor(ac2, off); ac3 += __shfl_xor(ac3, off);
    }
    float inv_s = (ssum > 0.f) ? 1.f / ssum : 0.f;
    float v0 = ac0 * inv_s + sb[ch + 0];
    float v1 = ac1 * inv_s + sb[ch + 1];
    float v2 = ac2 * inv_s + sb[ch + 2];
    float v3 = ac3 * inv_s + sb[ch + 3];
    // LayerNorm over 32 channels
    float s4 = v0 + v1 + v2 + v3;
    s4 += __shfl_xor(s4, 1); s4 += __shfl_xor(s4, 2); s4 += __shfl_xor(s4, 4);
    float mu = s4 * (1.f / 32.f);
    float d0 = v0 - mu, d1 = v1 - mu, d2 = v2 - mu, d3 = v3 - mu;
    float q4 = d0 * d0 + d1 * d1 + d2 * d2 + d3 * d3;
    q4 += __shfl_xor(q4, 1); q4 += __shfl_xor(q4, 2); q4 += __shfl_xor(q4, 4);
    float inv = rsqrtf(q4 * (1.f / 32.f) + 1e-5f);
    if (grp == 0) {
        float4 o;
        o.x = d0 * inv * sg[ch + 0] + sbe[ch + 0];
        o.y = d1 * inv * sg[ch + 1] + sbe[ch + 1];
        o.z = d2 * inv * sg[ch + 2] + sbe[ch + 2];
        o.w = d3 * inv * sg[ch + 3] + sbe[ch + 3];
        *(float4*)(out + (size_t)node * 32 + ch) = o;
    }
}

extern "C" void kernel_launch(void* const* d_in, const int* in_sizes, int n_in,
                              void* d_out, int out_size, void* d_ws, size_t ws_size,
                              hipStream_t stream) {
    const float* x    = (const float*)d_in[0];
    const int* ei     = (const int*)d_in[1];
    const float* Wl1  = (const float*)d_in[2];
    const float* Wr1  = (const float*)d_in[3];
    const float* att1 = (const float*)d_in[4];
    const float* b1   = (const float*)d_in[5];
    const float* g1   = (const float*)d_in[6];
    const float* be1  = (const float*)d_in[7];
    const float* Wl2  = (const float*)d_in[8];
    const float* Wr2  = (const float*)d_in[9];
    const float* att2 = (const float*)d_in[10];
    const float* b2   = (const float*)d_in[11];
    const float* g2   = (const float*)d_in[12];
    const float* be2  = (const float*)d_in[13];
    float* out = (float*)d_out;

    float* ws = (float*)d_ws;
    // Region A: xl1 [N*64]; after gather1 reused as xl2 [N*32] + xr2 [N*32]
    float* xl1 = ws;
    float* xl2 = xl1;
    float* xr2 = xl1 + (size_t)NN * 32;
    // Region B: h [N*64]
    float* h = xl1 + (size_t)NN * 64;
    // Int region
    int* deg = (int*)(h + (size_t)NN * 64);
    int* rowptr = deg + NN;
    int* cursor = rowptr + NN + 1;
    int* csr_src = cursor + NN;
    int* bsum = csr_src + NE;
    int* boff = bsum + NCHUNK;

    const int B = 256;

    // ---- CSR build (shared by both layers) ----
    hipMemsetAsync(deg, 0, (size_t)NN * sizeof(int), stream);
    hist_kernel<<<(NE + B - 1) / B, B, 0, stream>>>(ei, deg);
    scanA_kernel<<<NCHUNK, B, 0, stream>>>(deg, bsum);
    scanB_kernel<<<1, 64, 0, stream>>>(bsum, boff);
    scanC_kernel<<<NCHUNK, B, 0, stream>>>(deg, boff, rowptr, cursor);
    scatter_kernel<<<(NE + B - 1) / B, B, 0, stream>>>(ei, cursor, csr_src);

    // ---- layer 1 ----
    lin1_kernel<<<(NN * 64 + B - 1) / B, B, 0, stream>>>(x, Wl1, xl1);
    gather1_kernel<<<(NN + 3) / 4, B, 0, stream>>>(rowptr, csr_src, x, Wr1, att1, xl1,
                                                   b1, g1, be1, h);

    // ---- layer 2 ----
    lin2_kernel<<<(NN + 7) / 8, B, 0, stream>>>(h, Wl2, Wr2, xl2, xr2);
    gather2_kernel<<<(NN + 3) / 4, B, 0, stream>>>(rowptr, csr_src, xl2, xr2, att2,
                                                   b2, g2, be2, out);
}

// Round 5
// 261.485 us; speedup vs baseline: 9.5273x; 1.5093x over previous
//
#include <hip/hip_runtime.h>
#include <math.h>

#define NN 100000
#define NE 1600000
#define HID 64
#define OUTC 32
#define NEG 0.2f
#define NBUCK 196      // ceil(100000/512) buckets of 512 dst nodes
#define EPB 8000       // edges per partition block (NE/EPB = 200 blocks)

// ---------- CSR build: 2-level bucket sort ----------

__global__ __launch_bounds__(256) void bucketA_kernel(const int* __restrict__ ei,
                                                      int* __restrict__ gcount) {
    __shared__ int cnt[NBUCK];
    int tid = threadIdx.x;
    for (int i = tid; i < NBUCK; i += 256) cnt[i] = 0;
    __syncthreads();
    int base = blockIdx.x * EPB;
    const int* dstp = ei + NE;
    for (int i = tid; i < EPB; i += 256) atomicAdd(&cnt[dstp[base + i] >> 9], 1);
    __syncthreads();
    for (int i = tid; i < NBUCK; i += 256) atomicAdd(&gcount[i], cnt[i]);
}

__global__ void bucketScan_kernel(const int* __restrict__ gcount,
                                  int* __restrict__ gbase,
                                  int* __restrict__ gcursor) {
    int lane = threadIdx.x;  // 64 threads
    int carry = 0;
    for (int b0 = 0; b0 < NBUCK; b0 += 64) {
        int i = b0 + lane;
        int v = (i < NBUCK) ? gcount[i] : 0;
        int sv = v;
        for (int s = 1; s < 64; s <<= 1) {
            int t = __shfl_up(sv, s);
            if (lane >= s) sv += t;
        }
        if (i < NBUCK) {
            gbase[i] = carry + sv - v;
            gcursor[i] = carry + sv - v;
        }
        carry += __shfl(sv, 63);
    }
    if (lane == 0) gbase[NBUCK] = NE;
}

// partition edges into bucket-contiguous staging; pack (dst&511)<<17 | src (26 bits)
__global__ __launch_bounds__(256) void bucketB_kernel(const int* __restrict__ ei,
                                                      int* __restrict__ gcursor,
                                                      unsigned int* __restrict__ staging) {
    __shared__ int cnt[NBUCK];
    __shared__ int cur[NBUCK];
    int tid = threadIdx.x;
    for (int i = tid; i < NBUCK; i += 256) cnt[i] = 0;
    __syncthreads();
    int base = blockIdx.x * EPB;
    const int* dstp = ei + NE;
    for (int i = tid; i < EPB; i += 256) atomicAdd(&cnt[dstp[base + i] >> 9], 1);
    __syncthreads();
    for (int i = tid; i < NBUCK; i += 256) cur[i] = atomicAdd(&gcursor[i], cnt[i]);
    __syncthreads();
    for (int i = tid; i < EPB; i += 256) {
        int d = dstp[base + i];
        int s = ei[base + i];
        int b = d >> 9;
        int pos = atomicAdd(&cur[b], 1);
        staging[pos] = ((unsigned int)(d & 511) << 17) | (unsigned int)s;
    }
}

// per bucket: LDS node histogram + scan -> rowptr, then LDS-cursor scatter -> csr_src
__global__ __launch_bounds__(256) void bucketC_kernel(const unsigned int* __restrict__ staging,
                                                      const int* __restrict__ gbase,
                                                      int* __restrict__ rowptr,
                                                      int* __restrict__ csr_src) {
    int b = blockIdx.x;
    int node0 = b << 9;
    int nnode = min(512, NN - node0);
    int e0 = gbase[b], e1 = gbase[b + 1];
    __shared__ int deg[512];
    __shared__ int sbuf[256];
    int tid = threadIdx.x;
    deg[tid] = 0;
    deg[tid + 256] = 0;
    __syncthreads();
    for (int e = e0 + tid; e < e1; e += 256) atomicAdd(&deg[staging[e] >> 17], 1);
    __syncthreads();
    int d0 = deg[2 * tid], d1 = deg[2 * tid + 1];
    int tsum = d0 + d1;
    int run = tsum;
    sbuf[tid] = tsum;
    __syncthreads();
    for (int off = 1; off < 256; off <<= 1) {
        int u = (tid >= off) ? sbuf[tid - off] : 0;
        __syncthreads();
        run += u;
        sbuf[tid] = run;
        __syncthreads();
    }
    int eb = run - tsum;  // exclusive prefix of this thread's node pair
    deg[2 * tid] = eb;
    deg[2 * tid + 1] = eb + d0;
    if (2 * tid < nnode) rowptr[node0 + 2 * tid] = e0 + eb;
    if (2 * tid + 1 < nnode) rowptr[node0 + 2 * tid + 1] = e0 + eb + d0;
    if (b == NBUCK - 1 && tid == 0) rowptr[NN] = NE;
    __syncthreads();
    for (int e = e0 + tid; e < e1; e += 256) {
        unsigned int p = staging[e];
        int dl = p >> 17;
        int src = (int)(p & 0x1FFFFu);
        int pos = e0 + atomicAdd(&deg[dl], 1);
        csr_src[pos] = src;
    }
}

// ---------- layer 1 ----------

__global__ __launch_bounds__(256) void lin1_kernel(const float* __restrict__ x,
                                                   const float* __restrict__ Wl,
                                                   float* __restrict__ xl) {
    __shared__ float sWl[4 * HID];
    for (int i = threadIdx.x; i < 4 * HID; i += blockDim.x) sWl[i] = Wl[i];
    __syncthreads();
    int idx = blockIdx.x * blockDim.x + threadIdx.x;
    int stride = gridDim.x * blockDim.x;
    const float4* x4 = (const float4*)x;
    for (; idx < NN * HID; idx += stride) {
        int n = idx >> 6, c = idx & 63;
        float4 xv = x4[n];
        xl[idx] = xv.x * sWl[c] + xv.y * sWl[64 + c] + xv.z * sWl[128 + c] + xv.w * sWl[192 + c];
    }
}

// Fused GATv2 layer-1 pull: 1 wave per dst node, 4 edges in flight.
__global__ __launch_bounds__(256) void gather1_kernel(const int* __restrict__ rowptr,
                                                      const int* __restrict__ csr_src,
                                                      const float* __restrict__ x,
                                                      const float* __restrict__ Wr,
                                                      const float* __restrict__ att,
                                                      const float* __restrict__ xl,
                                                      const float* __restrict__ b1,
                                                      const float* __restrict__ g1,
                                                      const float* __restrict__ be1,
                                                      float* __restrict__ h) {
    __shared__ float sWr[4 * HID];
    __shared__ float satt[HID], sb[HID], sg[HID], sbe[HID];
    int tid = threadIdx.x;
    if (tid < 256) sWr[tid] = Wr[tid];
    if (tid < HID) {
        satt[tid] = att[tid];
        sb[tid] = b1[tid];
        sg[tid] = g1[tid];
        sbe[tid] = be1[tid];
    }
    __syncthreads();
    int node = blockIdx.x * 4 + (tid >> 6);
    if (node >= NN) return;
    int lane = tid & 63;
    int grp = lane >> 4;  // edge slot 0..3
    int sl = lane & 15;   // channel quad
    int ch = sl * 4;
    int p0 = rowptr[node], p1 = rowptr[node + 1];

    float4 xd = *(const float4*)(x + node * 4);
    float xr0 = xd.x * sWr[ch + 0] + xd.y * sWr[64 + ch + 0] + xd.z * sWr[128 + ch + 0] + xd.w * sWr[192 + ch + 0];
    float xr1 = xd.x * sWr[ch + 1] + xd.y * sWr[64 + ch + 1] + xd.z * sWr[128 + ch + 1] + xd.w * sWr[192 + ch + 1];
    float xr2 = xd.x * sWr[ch + 2] + xd.y * sWr[64 + ch + 2] + xd.z * sWr[128 + ch + 2] + xd.w * sWr[192 + ch + 2];
    float xr3 = xd.x * sWr[ch + 3] + xd.y * sWr[64 + ch + 3] + xd.z * sWr[128 + ch + 3] + xd.w * sWr[192 + ch + 3];
    float a0 = satt[ch + 0], a1 = satt[ch + 1], a2 = satt[ch + 2], a3 = satt[ch + 3];

    float ssum = 0.f;
    float ac0 = 0.f, ac1 = 0.f, ac2 = 0.f, ac3 = 0.f;
    for (int p = p0; p < p1; p += 64) {
        int cnt = min(64, p1 - p);
        int srcs = (lane < cnt) ? csr_src[p + lane] : 0;
        for (int j = 0; j < cnt; j += 4) {
            int idx = j + grp;
            bool ok = idx < cnt;
            int s = __shfl(srcs, ok ? idx : 0);
            float4 l4 = *(const float4*)(xl + (size_t)s * 64 + ch);
            float mm, vv;
            mm = l4.x + xr0; mm = mm > 0.f ? mm : NEG * mm; vv = mm * a0;
            mm = l4.y + xr1; mm = mm > 0.f ? mm : NEG * mm; vv += mm * a1;
            mm = l4.z + xr2; mm = mm > 0.f ? mm : NEG * mm; vv += mm * a2;
            mm = l4.w + xr3; mm = mm > 0.f ? mm : NEG * mm; vv += mm * a3;
            vv += __shfl_xor(vv, 1);
            vv += __shfl_xor(vv, 2);  // per-head logit (4 lanes = 16 ch)
            float ev = ok ? __expf(vv) : 0.f;
            ssum += ev;
            ac0 += ev * l4.x;
            ac1 += ev * l4.y;
            ac2 += ev * l4.z;
            ac3 += ev * l4.w;
        }
    }
    ssum += __shfl_xor(ssum, 16);
    ac0 += __shfl_xor(ac0, 16); ac1 += __shfl_xor(ac1, 16);
    ac2 += __shfl_xor(ac2, 16); ac3 += __shfl_xor(ac3, 16);
    ssum += __shfl_xor(ssum, 32);
    ac0 += __shfl_xor(ac0, 32); ac1 += __shfl_xor(ac1, 32);
    ac2 += __shfl_xor(ac2, 32); ac3 += __shfl_xor(ac3, 32);
    float inv_s = (ssum > 0.f) ? 1.f / ssum : 0.f;
    float v0 = ac0 * inv_s + sb[ch + 0];
    float v1 = ac1 * inv_s + sb[ch + 1];
    float v2 = ac2 * inv_s + sb[ch + 2];
    float v3 = ac3 * inv_s + sb[ch + 3];
    float s4 = v0 + v1 + v2 + v3;
    s4 += __shfl_xor(s4, 1); s4 += __shfl_xor(s4, 2);
    s4 += __shfl_xor(s4, 4); s4 += __shfl_xor(s4, 8);
    float mu = s4 * (1.f / 64.f);
    float d0 = v0 - mu, d1 = v1 - mu, d2 = v2 - mu, d3 = v3 - mu;
    float q4 = d0 * d0 + d1 * d1 + d2 * d2 + d3 * d3;
    q4 += __shfl_xor(q4, 1); q4 += __shfl_xor(q4, 2);
    q4 += __shfl_xor(q4, 4); q4 += __shfl_xor(q4, 8);
    float inv = rsqrtf(q4 * (1.f / 64.f) + 1e-5f);
    float y0 = d0 * inv * sg[ch + 0] + sbe[ch + 0];
    float y1 = d1 * inv * sg[ch + 1] + sbe[ch + 1];
    float y2 = d2 * inv * sg[ch + 2] + sbe[ch + 2];
    float y3 = d3 * inv * sg[ch + 3] + sbe[ch + 3];
    y0 = y0 > 0.f ? y0 : expm1f(y0);
    y1 = y1 > 0.f ? y1 : expm1f(y1);
    y2 = y2 > 0.f ? y2 : expm1f(y2);
    y3 = y3 > 0.f ? y3 : expm1f(y3);
    if (grp == 0) {
        float4 o = make_float4(y0, y1, y2, y3);
        *(float4*)(h + (size_t)node * 64 + ch) = o;
    }
}

// ---------- layer 2 ----------

__global__ __launch_bounds__(256) void lin2_kernel(const float* __restrict__ h,
                                                   const float* __restrict__ Wl,
                                                   const float* __restrict__ Wr,
                                                   float* __restrict__ xl2,
                                                   float* __restrict__ xr2) {
    __shared__ float sW[2 * HID * OUTC];
    __shared__ float sh[8 * HID];
    for (int i = threadIdx.x; i < HID * OUTC; i += blockDim.x) {
        sW[i] = Wl[i];
        sW[HID * OUTC + i] = Wr[i];
    }
    int node0 = blockIdx.x * 8;
    for (int i = threadIdx.x; i < 8 * HID; i += blockDim.x) {
        int n = node0 + (i >> 6);
        sh[i] = (n < NN) ? h[n * 64 + (i & 63)] : 0.f;
    }
    __syncthreads();
    int ln = threadIdx.x >> 5;
    int col = threadIdx.x & 31;
    int node = node0 + ln;
    if (node < NN) {
        float al = 0.f, ar = 0.f;
#pragma unroll
        for (int k = 0; k < HID; k++) {
            float hv = sh[ln * 64 + k];
            al += hv * sW[k * 32 + col];
            ar += hv * sW[HID * OUTC + k * 32 + col];
        }
        xl2[node * 32 + col] = al;
        xr2[node * 32 + col] = ar;
    }
}

// Fused GATv2 layer-2 pull: 1 wave per dst node, 8 edges in flight.
__global__ __launch_bounds__(256) void gather2_kernel(const int* __restrict__ rowptr,
                                                      const int* __restrict__ csr_src,
                                                      const float* __restrict__ xl2,
                                                      const float* __restrict__ xr2,
                                                      const float* __restrict__ att,
                                                      const float* __restrict__ b2,
                                                      const float* __restrict__ g2,
                                                      const float* __restrict__ be2,
                                                      float* __restrict__ out) {
    __shared__ float satt[OUTC], sb[OUTC], sg[OUTC], sbe[OUTC];
    int tid = threadIdx.x;
    if (tid < OUTC) {
        satt[tid] = att[tid];
        sb[tid] = b2[tid];
        sg[tid] = g2[tid];
        sbe[tid] = be2[tid];
    }
    __syncthreads();
    int node = blockIdx.x * 4 + (tid >> 6);
    if (node >= NN) return;
    int lane = tid & 63;
    int grp = lane >> 3;  // edge slot 0..7
    int sl = lane & 7;    // channel quad
    int ch = sl * 4;
    int p0 = rowptr[node], p1 = rowptr[node + 1];

    float4 xr = *(const float4*)(xr2 + (size_t)node * 32 + ch);
    float a0 = satt[ch + 0], a1 = satt[ch + 1], a2 = satt[ch + 2], a3 = satt[ch + 3];

    float ssum = 0.f;
    float ac0 = 0.f, ac1 = 0.f, ac2 = 0.f, ac3 = 0.f;
    for (int p = p0; p < p1; p += 64) {
        int cnt = min(64, p1 - p);
        int srcs = (lane < cnt) ? csr_src[p + lane] : 0;
        for (int j = 0; j < cnt; j += 8) {
            int idx = j + grp;
            bool ok = idx < cnt;
            int s = __shfl(srcs, ok ? idx : 0);
            float4 l4 = *(const float4*)(xl2 + (size_t)s * 32 + ch);
            float mm, vv;
            mm = l4.x + xr.x; mm = mm > 0.f ? mm : NEG * mm; vv = mm * a0;
            mm = l4.y + xr.y; mm = mm > 0.f ? mm : NEG * mm; vv += mm * a1;
            mm = l4.z + xr.z; mm = mm > 0.f ? mm : NEG * mm; vv += mm * a2;
            mm = l4.w + xr.w; mm = mm > 0.f ? mm : NEG * mm; vv += mm * a3;
            vv += __shfl_xor(vv, 1);
            vv += __shfl_xor(vv, 2);
            vv += __shfl_xor(vv, 4);  // 8 lanes = full 32-ch logit
            float ev = ok ? __expf(vv) : 0.f;
            ssum += ev;
            ac0 += ev * l4.x;
            ac1 += ev * l4.y;
            ac2 += ev * l4.z;
            ac3 += ev * l4.w;
        }
    }
    for (int off = 8; off < 64; off <<= 1) {
        ssum += __shfl_xor(ssum, off);
        ac0 += __shfl_xor(ac0, off); ac1 += __shfl_xor(ac1, off);
        ac2 += __shfl_xor(ac2, off); ac3 += __shfl_xor(ac3, off);
    }
    float inv_s = (ssum > 0.f) ? 1.f / ssum : 0.f;
    float v0 = ac0 * inv_s + sb[ch + 0];
    float v1 = ac1 * inv_s + sb[ch + 1];
    float v2 = ac2 * inv_s + sb[ch + 2];
    float v3 = ac3 * inv_s + sb[ch + 3];
    float s4 = v0 + v1 + v2 + v3;
    s4 += __shfl_xor(s4, 1); s4 += __shfl_xor(s4, 2); s4 += __shfl_xor(s4, 4);
    float mu = s4 * (1.f / 32.f);
    float d0 = v0 - mu, d1 = v1 - mu, d2 = v2 - mu, d3 = v3 - mu;
    float q4 = d0 * d0 + d1 * d1 + d2 * d2 + d3 * d3;
    q4 += __shfl_xor(q4, 1); q4 += __shfl_xor(q4, 2); q4 += __shfl_xor(q4, 4);
    float inv = rsqrtf(q4 * (1.f / 32.f) + 1e-5f);
    if (grp == 0) {
        float4 o;
        o.x = d0 * inv * sg[ch + 0] + sbe[ch + 0];
        o.y = d1 * inv * sg[ch + 1] + sbe[ch + 1];
        o.z = d2 * inv * sg[ch + 2] + sbe[ch + 2];
        o.w = d3 * inv * sg[ch + 3] + sbe[ch + 3];
        *(float4*)(out + (size_t)node * 32 + ch) = o;
    }
}

extern "C" void kernel_launch(void* const* d_in, const int* in_sizes, int n_in,
                              void* d_out, int out_size, void* d_ws, size_t ws_size,
                              hipStream_t stream) {
    const float* x    = (const float*)d_in[0];
    const int* ei     = (const int*)d_in[1];
    const float* Wl1  = (const float*)d_in[2];
    const float* Wr1  = (const float*)d_in[3];
    const float* att1 = (const float*)d_in[4];
    const float* b1   = (const float*)d_in[5];
    const float* g1   = (const float*)d_in[6];
    const float* be1  = (const float*)d_in[7];
    const float* Wl2  = (const float*)d_in[8];
    const float* Wr2  = (const float*)d_in[9];
    const float* att2 = (const float*)d_in[10];
    const float* b2   = (const float*)d_in[11];
    const float* g2   = (const float*)d_in[12];
    const float* be2  = (const float*)d_in[13];
    float* out = (float*)d_out;

    float* ws = (float*)d_ws;
    float* xl1 = ws;                               // N*64; reused as xl2/xr2
    float* xl2 = xl1;
    float* xr2 = xl1 + (size_t)NN * 32;
    float* h = xl1 + (size_t)NN * 64;              // N*64
    int* rowptr = (int*)(h + (size_t)NN * 64);     // N+1
    int* csr_src = rowptr + NN + 1;                // E
    unsigned int* staging = (unsigned int*)(csr_src + NE);  // E
    int* gcount = (int*)(staging + NE);            // NBUCK
    int* gbase = gcount + NBUCK;                   // NBUCK+1
    int* gcursor = gbase + NBUCK + 1;              // NBUCK

    const int B = 256;

    // ---- CSR build: bucket sort (shared by both layers) ----
    hipMemsetAsync(gcount, 0, NBUCK * sizeof(int), stream);
    bucketA_kernel<<<NE / EPB, B, 0, stream>>>(ei, gcount);
    bucketScan_kernel<<<1, 64, 0, stream>>>(gcount, gbase, gcursor);
    bucketB_kernel<<<NE / EPB, B, 0, stream>>>(ei, gcursor, staging);
    bucketC_kernel<<<NBUCK, B, 0, stream>>>(staging, gbase, rowptr, csr_src);

    // ---- layer 1 ----
    lin1_kernel<<<(NN * 64 + B - 1) / B, B, 0, stream>>>(x, Wl1, xl1);
    gather1_kernel<<<(NN + 3) / 4, B, 0, stream>>>(rowptr, csr_src, x, Wr1, att1, xl1,
                                                   b1, g1, be1, h);

    // ---- layer 2 ----
    lin2_kernel<<<(NN + 7) / 8, B, 0, stream>>>(h, Wl2, Wr2, xl2, xr2);
    gather2_kernel<<<(NN + 3) / 4, B, 0, stream>>>(rowptr, csr_src, xl2, xr2, att2,
                                                   b2, g2, be2, out);
}

// Round 6
// 236.585 us; speedup vs baseline: 10.5301x; 1.1053x over previous
//
#include <hip/hip_runtime.h>
#include <math.h>

#define NN 100000
#define NE 1600000
#define HID 64
#define OUTC 32
#define NEG 0.2f
#define NBUCK 196      // ceil(100000/512) buckets of 512 dst nodes
#define EPB 8000       // edges per partition block
#define NPB 200        // NE / EPB partition blocks

// ---------- CSR build: 2-level bucket sort ----------

// count per (bucket, partition-block); also bucket totals
__global__ __launch_bounds__(256) void bucketA_kernel(const int* __restrict__ ei,
                                                      int* __restrict__ gcount,
                                                      int* __restrict__ blkcnt) {
    __shared__ int cnt[NBUCK];
    int tid = threadIdx.x;
    for (int i = tid; i < NBUCK; i += 256) cnt[i] = 0;
    __syncthreads();
    int base = blockIdx.x * EPB;
    const int* dstp = ei + NE;
    for (int i = tid; i < EPB; i += 256) atomicAdd(&cnt[dstp[base + i] >> 9], 1);
    __syncthreads();
    for (int i = tid; i < NBUCK; i += 256) {
        blkcnt[i * NPB + blockIdx.x] = cnt[i];
        atomicAdd(&gcount[i], cnt[i]);
    }
}

// per bucket: gbase (sum of earlier bucket totals) + exclusive scan over partition
// blocks -> absolute scatter cursors; also writes gbase array for bucketC.
__global__ __launch_bounds__(256) void scanBlk_kernel(const int* __restrict__ gcount,
                                                      const int* __restrict__ blkcnt,
                                                      int* __restrict__ cursors,
                                                      int* __restrict__ gbase_arr) {
    __shared__ int sbuf[256];
    __shared__ int swave[4];
    int b = blockIdx.x;
    int tid = threadIdx.x;
    int gv = (tid < b) ? gcount[tid] : 0;
    for (int off = 1; off < 64; off <<= 1) gv += __shfl_xor(gv, off);
    if ((tid & 63) == 0) swave[tid >> 6] = gv;
    __syncthreads();
    int gbase = swave[0] + swave[1] + swave[2] + swave[3];
    int v = (tid < NPB) ? blkcnt[b * NPB + tid] : 0;
    int run = v;
    sbuf[tid] = run;
    __syncthreads();
    for (int off = 1; off < 256; off <<= 1) {
        int u = (tid >= off) ? sbuf[tid - off] : 0;
        __syncthreads();
        run += u;
        sbuf[tid] = run;
        __syncthreads();
    }
    if (tid < NPB) cursors[b * NPB + tid] = gbase + run - v;
    if (tid == 0) {
        gbase_arr[b] = gbase;
        if (b == 0) gbase_arr[NBUCK] = NE;
    }
}

// partition edges into bucket-contiguous staging; pack (dst&511)<<17 | src
__global__ __launch_bounds__(256) void bucketB_kernel(const int* __restrict__ ei,
                                                      const int* __restrict__ cursors,
                                                      unsigned int* __restrict__ staging) {
    __shared__ int cur[NBUCK];
    int tid = threadIdx.x;
    for (int i = tid; i < NBUCK; i += 256) cur[i] = cursors[i * NPB + blockIdx.x];
    __syncthreads();
    int base = blockIdx.x * EPB;
    const int* dstp = ei + NE;
    for (int i = tid; i < EPB; i += 256) {
        int d = dstp[base + i];
        int s = ei[base + i];
        int pos = atomicAdd(&cur[d >> 9], 1);
        staging[pos] = ((unsigned int)(d & 511) << 17) | (unsigned int)s;
    }
}

// per bucket: LDS node histogram + scan -> rowptr, then LDS-cursor scatter -> csr_src
__global__ __launch_bounds__(256) void bucketC_kernel(const unsigned int* __restrict__ staging,
                                                      const int* __restrict__ gbase,
                                                      int* __restrict__ rowptr,
                                                      int* __restrict__ csr_src) {
    int b = blockIdx.x;
    int node0 = b << 9;
    int nnode = min(512, NN - node0);
    int e0 = gbase[b], e1 = gbase[b + 1];
    __shared__ int deg[512];
    __shared__ int sbuf[256];
    int tid = threadIdx.x;
    deg[tid] = 0;
    deg[tid + 256] = 0;
    __syncthreads();
    for (int e = e0 + tid; e < e1; e += 256) atomicAdd(&deg[staging[e] >> 17], 1);
    __syncthreads();
    int d0 = deg[2 * tid], d1 = deg[2 * tid + 1];
    int tsum = d0 + d1;
    int run = tsum;
    sbuf[tid] = tsum;
    __syncthreads();
    for (int off = 1; off < 256; off <<= 1) {
        int u = (tid >= off) ? sbuf[tid - off] : 0;
        __syncthreads();
        run += u;
        sbuf[tid] = run;
        __syncthreads();
    }
    int eb = run - tsum;
    deg[2 * tid] = eb;
    deg[2 * tid + 1] = eb + d0;
    if (2 * tid < nnode) rowptr[node0 + 2 * tid] = e0 + eb;
    if (2 * tid + 1 < nnode) rowptr[node0 + 2 * tid + 1] = e0 + eb + d0;
    if (b == NBUCK - 1 && tid == 0) rowptr[NN] = NE;
    __syncthreads();
    for (int e = e0 + tid; e < e1; e += 256) {
        unsigned int p = staging[e];
        int dl = p >> 17;
        int src = (int)(p & 0x1FFFFu);
        int pos = e0 + atomicAdd(&deg[dl], 1);
        csr_src[pos] = src;
    }
}

// ---------- layer 1 ----------

__global__ __launch_bounds__(256) void lin1_kernel(const float* __restrict__ x,
                                                   const float* __restrict__ Wl,
                                                   float* __restrict__ xl) {
    __shared__ float sWl[4 * HID];
    for (int i = threadIdx.x; i < 4 * HID; i += blockDim.x) sWl[i] = Wl[i];
    __syncthreads();
    int idx = blockIdx.x * blockDim.x + threadIdx.x;
    int stride = gridDim.x * blockDim.x;
    const float4* x4 = (const float4*)x;
    for (; idx < NN * HID; idx += stride) {
        int n = idx >> 6, c = idx & 63;
        float4 xv = x4[n];
        xl[idx] = xv.x * sWl[c] + xv.y * sWl[64 + c] + xv.z * sWl[128 + c] + xv.w * sWl[192 + c];
    }
}

#define PROC1(L, IDX)                                                         \
    {                                                                         \
        float mm, vv;                                                         \
        mm = L.x + xr0; mm = fmaxf(mm, NEG * mm); vv = mm * a0;               \
        mm = L.y + xr1; mm = fmaxf(mm, NEG * mm); vv += mm * a1;              \
        mm = L.z + xr2; mm = fmaxf(mm, NEG * mm); vv += mm * a2;              \
        mm = L.w + xr3; mm = fmaxf(mm, NEG * mm); vv += mm * a3;              \
        vv += __shfl_xor(vv, 1);                                              \
        vv += __shfl_xor(vv, 2);                                              \
        float ev = ((IDX) < cnt) ? __expf(vv) : 0.f;                          \
        ssum += ev;                                                           \
        ac0 += ev * L.x; ac1 += ev * L.y; ac2 += ev * L.z; ac3 += ev * L.w;   \
    }

// Fused GATv2 layer-1 pull: 1 wave per dst node, 16 edges per pipelined window.
__global__ __launch_bounds__(256) void gather1_kernel(const int* __restrict__ rowptr,
                                                      const int* __restrict__ csr_src,
                                                      const float* __restrict__ x,
                                                      const float* __restrict__ Wr,
                                                      const float* __restrict__ att,
                                                      const float* __restrict__ xl,
                                                      const float* __restrict__ b1,
                                                      const float* __restrict__ g1,
                                                      const float* __restrict__ be1,
                                                      float* __restrict__ h) {
    __shared__ float sWr[4 * HID];
    __shared__ float satt[HID], sb[HID], sg[HID], sbe[HID];
    int tid = threadIdx.x;
    if (tid < 256) sWr[tid] = Wr[tid];
    if (tid < HID) {
        satt[tid] = att[tid];
        sb[tid] = b1[tid];
        sg[tid] = g1[tid];
        sbe[tid] = be1[tid];
    }
    __syncthreads();
    int node = blockIdx.x * 4 + (tid >> 6);
    if (node >= NN) return;
    int lane = tid & 63;
    int grp = lane >> 4;  // edge slot 0..3
    int ch = (lane & 15) * 4;
    int p0 = rowptr[node], p1 = rowptr[node + 1];

    float4 xd = *(const float4*)(x + node * 4);
    float xr0 = xd.x * sWr[ch + 0] + xd.y * sWr[64 + ch + 0] + xd.z * sWr[128 + ch + 0] + xd.w * sWr[192 + ch + 0];
    float xr1 = xd.x * sWr[ch + 1] + xd.y * sWr[64 + ch + 1] + xd.z * sWr[128 + ch + 1] + xd.w * sWr[192 + ch + 1];
    float xr2 = xd.x * sWr[ch + 2] + xd.y * sWr[64 + ch + 2] + xd.z * sWr[128 + ch + 2] + xd.w * sWr[192 + ch + 2];
    float xr3 = xd.x * sWr[ch + 3] + xd.y * sWr[64 + ch + 3] + xd.z * sWr[128 + ch + 3] + xd.w * sWr[192 + ch + 3];
    float a0 = satt[ch + 0], a1 = satt[ch + 1], a2 = satt[ch + 2], a3 = satt[ch + 3];

    float ssum = 0.f;
    float ac0 = 0.f, ac1 = 0.f, ac2 = 0.f, ac3 = 0.f;
    for (int p = p0; p < p1; p += 64) {
        int cnt = min(64, p1 - p);
        int srcs = (lane < cnt) ? csr_src[p + lane] : 0;
        for (int j = 0; j < cnt; j += 16) {
            int s0 = __shfl(srcs, j + grp);
            int s1 = __shfl(srcs, j + 4 + grp);
            int s2 = __shfl(srcs, j + 8 + grp);
            int s3 = __shfl(srcs, j + 12 + grp);
            float4 L0 = *(const float4*)(xl + (size_t)s0 * 64 + ch);
            float4 L1 = *(const float4*)(xl + (size_t)s1 * 64 + ch);
            float4 L2 = *(const float4*)(xl + (size_t)s2 * 64 + ch);
            float4 L3 = *(const float4*)(xl + (size_t)s3 * 64 + ch);
            PROC1(L0, j + grp)
            PROC1(L1, j + 4 + grp)
            PROC1(L2, j + 8 + grp)
            PROC1(L3, j + 12 + grp)
        }
    }
    ssum += __shfl_xor(ssum, 16);
    ac0 += __shfl_xor(ac0, 16); ac1 += __shfl_xor(ac1, 16);
    ac2 += __shfl_xor(ac2, 16); ac3 += __shfl_xor(ac3, 16);
    ssum += __shfl_xor(ssum, 32);
    ac0 += __shfl_xor(ac0, 32); ac1 += __shfl_xor(ac1, 32);
    ac2 += __shfl_xor(ac2, 32); ac3 += __shfl_xor(ac3, 32);
    float inv_s = (p1 > p0) ? __builtin_amdgcn_rcpf(ssum) : 0.f;
    float v0 = ac0 * inv_s + sb[ch + 0];
    float v1 = ac1 * inv_s + sb[ch + 1];
    float v2 = ac2 * inv_s + sb[ch + 2];
    float v3 = ac3 * inv_s + sb[ch + 3];
    float s4 = v0 + v1 + v2 + v3;
    s4 += __shfl_xor(s4, 1); s4 += __shfl_xor(s4, 2);
    s4 += __shfl_xor(s4, 4); s4 += __shfl_xor(s4, 8);
    float mu = s4 * (1.f / 64.f);
    float d0 = v0 - mu, d1 = v1 - mu, d2 = v2 - mu, d3 = v3 - mu;
    float q4 = d0 * d0 + d1 * d1 + d2 * d2 + d3 * d3;
    q4 += __shfl_xor(q4, 1); q4 += __shfl_xor(q4, 2);
    q4 += __shfl_xor(q4, 4); q4 += __shfl_xor(q4, 8);
    float inv = __builtin_amdgcn_rsqf(q4 * (1.f / 64.f) + 1e-5f);
    float y0 = d0 * inv * sg[ch + 0] + sbe[ch + 0];
    float y1 = d1 * inv * sg[ch + 1] + sbe[ch + 1];
    float y2 = d2 * inv * sg[ch + 2] + sbe[ch + 2];
    float y3 = d3 * inv * sg[ch + 3] + sbe[ch + 3];
    y0 = y0 > 0.f ? y0 : (__expf(y0) - 1.f);
    y1 = y1 > 0.f ? y1 : (__expf(y1) - 1.f);
    y2 = y2 > 0.f ? y2 : (__expf(y2) - 1.f);
    y3 = y3 > 0.f ? y3 : (__expf(y3) - 1.f);
    if (grp == 0) {
        float4 o = make_float4(y0, y1, y2, y3);
        *(float4*)(h + (size_t)node * 64 + ch) = o;
    }
}

// ---------- layer 2 ----------

__global__ __launch_bounds__(256) void lin2_kernel(const float* __restrict__ h,
                                                   const float* __restrict__ Wl,
                                                   const float* __restrict__ Wr,
                                                   float* __restrict__ xl2,
                                                   float* __restrict__ xr2) {
    __shared__ float sW[2 * HID * OUTC];
    __shared__ float sh[8 * HID];
    for (int i = threadIdx.x; i < HID * OUTC; i += blockDim.x) {
        sW[i] = Wl[i];
        sW[HID * OUTC + i] = Wr[i];
    }
    int node0 = blockIdx.x * 8;
    for (int i = threadIdx.x; i < 8 * HID; i += blockDim.x) {
        int n = node0 + (i >> 6);
        sh[i] = (n < NN) ? h[n * 64 + (i & 63)] : 0.f;
    }
    __syncthreads();
    int ln = threadIdx.x >> 5;
    int col = threadIdx.x & 31;
    int node = node0 + ln;
    if (node < NN) {
        float al = 0.f, ar = 0.f;
#pragma unroll
        for (int k = 0; k < HID; k++) {
            float hv = sh[ln * 64 + k];
            al += hv * sW[k * 32 + col];
            ar += hv * sW[HID * OUTC + k * 32 + col];
        }
        xl2[node * 32 + col] = al;
        xr2[node * 32 + col] = ar;
    }
}

#define PROC2(L, IDX)                                                         \
    {                                                                         \
        float mm, vv;                                                         \
        mm = L.x + xr.x; mm = fmaxf(mm, NEG * mm); vv = mm * a0;              \
        mm = L.y + xr.y; mm = fmaxf(mm, NEG * mm); vv += mm * a1;             \
        mm = L.z + xr.z; mm = fmaxf(mm, NEG * mm); vv += mm * a2;             \
        mm = L.w + xr.w; mm = fmaxf(mm, NEG * mm); vv += mm * a3;             \
        vv += __shfl_xor(vv, 1);                                              \
        vv += __shfl_xor(vv, 2);                                              \
        vv += __shfl_xor(vv, 4);                                              \
        float ev = ((IDX) < cnt) ? __expf(vv) : 0.f;                          \
        ssum += ev;                                                           \
        ac0 += ev * L.x; ac1 += ev * L.y; ac2 += ev * L.z; ac3 += ev * L.w;   \
    }

// Fused GATv2 layer-2 pull: 1 wave per dst node, 16 edges per pipelined window.
__global__ __launch_bounds__(256) void gather2_kernel(const int* __restrict__ rowptr,
                                                      const int* __restrict__ csr_src,
                                                      const float* __restrict__ xl2,
                                                      const float* __restrict__ xr2,
                                                      const float* __restrict__ att,
                                                      const float* __restrict__ b2,
                                                      const float* __restrict__ g2,
                                                      const float* __restrict__ be2,
                                                      float* __restrict__ out) {
    __shared__ float satt[OUTC], sb[OUTC], sg[OUTC], sbe[OUTC];
    int tid = threadIdx.x;
    if (tid < OUTC) {
        satt[tid] = att[tid];
        sb[tid] = b2[tid];
        sg[tid] = g2[tid];
        sbe[tid] = be2[tid];
    }
    __syncthreads();
    int node = blockIdx.x * 4 + (tid >> 6);
    if (node >= NN) return;
    int lane = tid & 63;
    int grp = lane >> 3;  // edge slot 0..7
    int ch = (lane & 7) * 4;
    int p0 = rowptr[node], p1 = rowptr[node + 1];

    float4 xr = *(const float4*)(xr2 + (size_t)node * 32 + ch);
    float a0 = satt[ch + 0], a1 = satt[ch + 1], a2 = satt[ch + 2], a3 = satt[ch + 3];

    float ssum = 0.f;
    float ac0 = 0.f, ac1 = 0.f, ac2 = 0.f, ac3 = 0.f;
    for (int p = p0; p < p1; p += 64) {
        int cnt = min(64, p1 - p);
        int srcs = (lane < cnt) ? csr_src[p + lane] : 0;
        for (int j = 0; j < cnt; j += 16) {
            int s0 = __shfl(srcs, j + grp);
            int s1 = __shfl(srcs, j + 8 + grp);
            float4 L0 = *(const float4*)(xl2 + (size_t)s0 * 32 + ch);
            float4 L1 = *(const float4*)(xl2 + (size_t)s1 * 32 + ch);
            PROC2(L0, j + grp)
            PROC2(L1, j + 8 + grp)
        }
    }
    for (int off = 8; off < 64; off <<= 1) {
        ssum += __shfl_xor(ssum, off);
        ac0 += __shfl_xor(ac0, off); ac1 += __shfl_xor(ac1, off);
        ac2 += __shfl_xor(ac2, off); ac3 += __shfl_xor(ac3, off);
    }
    float inv_s = (p1 > p0) ? __builtin_amdgcn_rcpf(ssum) : 0.f;
    float v0 = ac0 * inv_s + sb[ch + 0];
    float v1 = ac1 * inv_s + sb[ch + 1];
    float v2 = ac2 * inv_s + sb[ch + 2];
    float v3 = ac3 * inv_s + sb[ch + 3];
    float s4 = v0 + v1 + v2 + v3;
    s4 += __shfl_xor(s4, 1); s4 += __shfl_xor(s4, 2); s4 += __shfl_xor(s4, 4);
    float mu = s4 * (1.f / 32.f);
    float d0 = v0 - mu, d1 = v1 - mu, d2 = v2 - mu, d3 = v3 - mu;
    float q4 = d0 * d0 + d1 * d1 + d2 * d2 + d3 * d3;
    q4 += __shfl_xor(q4, 1); q4 += __shfl_xor(q4, 2); q4 += __shfl_xor(q4, 4);
    float inv = __builtin_amdgcn_rsqf(q4 * (1.f / 32.f) + 1e-5f);
    if (grp == 0) {
        float4 o;
        o.x = d0 * inv * sg[ch + 0] + sbe[ch + 0];
        o.y = d1 * inv * sg[ch + 1] + sbe[ch + 1];
        o.z = d2 * inv * sg[ch + 2] + sbe[ch + 2];
        o.w = d3 * inv * sg[ch + 3] + sbe[ch + 3];
        *(float4*)(out + (size_t)node * 32 + ch) = o;
    }
}

extern "C" void kernel_launch(void* const* d_in, const int* in_sizes, int n_in,
                              void* d_out, int out_size, void* d_ws, size_t ws_size,
                              hipStream_t stream) {
    const float* x    = (const float*)d_in[0];
    const int* ei     = (const int*)d_in[1];
    const float* Wl1  = (const float*)d_in[2];
    const float* Wr1  = (const float*)d_in[3];
    const float* att1 = (const float*)d_in[4];
    const float* b1   = (const float*)d_in[5];
    const float* g1   = (const float*)d_in[6];
    const float* be1  = (const float*)d_in[7];
    const float* Wl2  = (const float*)d_in[8];
    const float* Wr2  = (const float*)d_in[9];
    const float* att2 = (const float*)d_in[10];
    const float* b2   = (const float*)d_in[11];
    const float* g2   = (const float*)d_in[12];
    const float* be2  = (const float*)d_in[13];
    float* out = (float*)d_out;

    float* ws = (float*)d_ws;
    float* xl1 = ws;                               // N*64; reused as xl2/xr2
    float* xl2 = xl1;
    float* xr2 = xl1 + (size_t)NN * 32;
    float* h = xl1 + (size_t)NN * 64;              // N*64
    int* rowptr = (int*)(h + (size_t)NN * 64);     // N+1
    int* csr_src = rowptr + NN + 1;                // E
    unsigned int* staging = (unsigned int*)(csr_src + NE);  // E
    int* gcount = (int*)(staging + NE);            // NBUCK
    int* gbase = gcount + NBUCK;                   // NBUCK+1
    int* blkcnt = gbase + NBUCK + 1;               // NBUCK*NPB
    int* cursors = blkcnt + NBUCK * NPB;           // NBUCK*NPB

    const int B = 256;

    // ---- CSR build: bucket sort (shared by both layers) ----
    hipMemsetAsync(gcount, 0, NBUCK * sizeof(int), stream);
    bucketA_kernel<<<NPB, B, 0, stream>>>(ei, gcount, blkcnt);
    scanBlk_kernel<<<NBUCK, B, 0, stream>>>(gcount, blkcnt, cursors, gbase);
    bucketB_kernel<<<NPB, B, 0, stream>>>(ei, cursors, staging);
    bucketC_kernel<<<NBUCK, B, 0, stream>>>(staging, gbase, rowptr, csr_src);

    // ---- layer 1 ----
    lin1_kernel<<<(NN * 64 + B - 1) / B, B, 0, stream>>>(x, Wl1, xl1);
    gather1_kernel<<<(NN + 3) / 4, B, 0, stream>>>(rowptr, csr_src, x, Wr1, att1, xl1,
                                                   b1, g1, be1, h);

    // ---- layer 2 ----
    lin2_kernel<<<(NN + 7) / 8, B, 0, stream>>>(h, Wl2, Wr2, xl2, xr2);
    gather2_kernel<<<(NN + 3) / 4, B, 0, stream>>>(rowptr, csr_src, xl2, xr2, att2,
                                                   b2, g2, be2, out);
}